// Round 2
// 744.506 us; speedup vs baseline: 1.0793x; 1.0793x over previous
//
#include <hip/hip_runtime.h>

#define NN 768
#define CIN 128
#define COUT 64
#define CDG 39
#define CAA 22
#define CESM 1280

typedef __attribute__((ext_vector_type(8))) short short8;
typedef __attribute__((ext_vector_type(4))) float f32x4;

__device__ __forceinline__ unsigned short f2bf(float f) {
  union { float f; unsigned int i; } c; c.f = f;
  unsigned int u = c.i;
  u += 0x7fffu + ((u >> 16) & 1u);
  return (unsigned short)(u >> 16);
}
__device__ __forceinline__ unsigned int pk(float a, float b) {
  return (unsigned int)f2bf(a) | ((unsigned int)f2bf(b) << 16);
}

struct Args {
  const float *td, *aa, *q, *pbm, *bbm, *mc, *ux, *uy, *uz, *esm;
  const float *w_dgram, *b_dgram, *w_aa1, *b_aa1, *w_aa2, *b_aa2;
  const float *ln_g, *ln_b, *w_q, *b_q;
  const float *w_pbm, *b_pbm, *w_x, *b_x, *w_y, *b_y, *w_z, *b_z, *w_bb, *b_bb;
  const float *w_esm1, *b_esm1, *w_esm2, *b_esm2;
  float* out;
  float* row_vec; float* col_vec; unsigned short* b_pack;
};

// ---------------------------------------------------------------------------
// Kernel 1: per-residue row/col vectors (aa + esm projections + all biases)
// and the packed B matrix (192 x 64) bf16 in 16x16x32 MFMA B-fragment order.
// B row k: [0,128)=ln_g*w_q (LN gain folded in), [128,167)=w_dgram,
// 167=w_pbm, 168..170=w_x/y/z, 171=w_bb, [172,192)=zero.
// row_vec bias additionally absorbs ln_b @ w_q (LN shift folded in).
// ---------------------------------------------------------------------------
__global__ __launch_bounds__(256) void k_pre(Args a) {
  const int b = blockIdx.x;
  const int tid = threadIdx.x;
  if (b == NN) {
    // B_pack element e = ((q*4+t)*64 + lane)*8 + j  holds  B[k][n] as bf16
    for (int e = tid; e < 12288; e += 256) {
      int jj = e & 7;
      int lane = (e >> 3) & 63;
      int qt = e >> 9;
      int q = qt >> 2, t = qt & 3;
      int k = q * 32 + ((lane >> 4) << 3) + jj;
      int n = t * 16 + (lane & 15);
      float v = 0.f;
      if (k < CIN) v = a.ln_g[k] * a.w_q[k * COUT + n];
      else if (k < CIN + CDG) v = a.w_dgram[(k - CIN) * COUT + n];
      else if (k == 167) v = a.w_pbm[n];
      else if (k == 168) v = a.w_x[n];
      else if (k == 169) v = a.w_y[n];
      else if (k == 170) v = a.w_z[n];
      else if (k == 171) v = a.w_bb[n];
      a.b_pack[e] = f2bf(v);
    }
    return;
  }
  const int wv = tid >> 6, lane = tid & 63;
  float acc1 = 0.f, acc2 = 0.f;
  const int KT = CAA + CESM;           // 1302
  const int SL = (KT + 3) / 4;         // 326
  int k0 = wv * SL;
  int k1 = k0 + SL; if (k1 > KT) k1 = KT;
  for (int k = k0; k < k1; ++k) {
    float v; const float *w1, *w2;
    if (k < CAA) { v = a.aa[b * CAA + k]; w1 = a.w_aa1 + k * COUT; w2 = a.w_aa2 + k * COUT; }
    else { int e = k - CAA; v = a.esm[b * CESM + e]; w1 = a.w_esm1 + e * COUT; w2 = a.w_esm2 + e * COUT; }
    acc1 += v * w1[lane];
    acc2 += v * w2[lane];
  }
  __shared__ float red1[4][64];
  __shared__ float red2[4][64];
  red1[wv][lane] = acc1; red2[wv][lane] = acc2;
  __syncthreads();
  if (wv == 0) {
    float r1 = red1[0][lane] + red1[1][lane] + red1[2][lane] + red1[3][lane];
    float r2 = red2[0][lane] + red2[1][lane] + red2[2][lane] + red2[3][lane];
    // ln_b @ w_q folded into the row bias (zero for ln_b == 0)
    float bq = 0.f;
    for (int c = 0; c < CIN; ++c) bq += a.ln_b[c] * a.w_q[c * COUT + lane];
    float br = a.b_aa1[lane] + a.b_esm1[lane] + a.b_dgram[lane] +
               a.b_pbm[lane] + a.b_x[lane] + a.b_y[lane] +
               a.b_z[lane] + a.b_bb[lane] + a.b_q[lane] + bq;
    float bc = a.b_aa2[lane] + a.b_esm2[lane];
    a.row_vec[b * COUT + lane] = r1 + br;
    a.col_vec[b * COUT + lane] = r2 + bc;
  }
}

// ---------------------------------------------------------------------------
// Kernel 2: main fused kernel. One block = 64 pairs (fixed i, 64 j) x 64 out.
// q path: each lane loads its OWN MFMA A-fragment rows straight from global
// (row = wv*16 + m, cols quad*8 + qq*32), LayerNorm via shfl_xor(16/32)
// across the 4 lanes sharing a row, converts in-register. No LDS for q.
// LDS: B (24.6 KB, baseline path) + A2 64x72 tile for cols 128..191
// ([0,39)=td*bb2, 39=pb2, 40..42=unit*bb2, 43=bb2, [44,64)=0) + masks
// = 34.3 KB -> 4 blocks/CU (was 3 at 50.7 KB).
// ---------------------------------------------------------------------------
__global__ __launch_bounds__(256, 4) void k_main(Args a) {
  const int jt = blockIdx.x;           // 0..11
  const int i  = blockIdx.y;           // 0..767
  const int jbase = jt * 64;
  const int tid = threadIdx.x;
  const int wv = tid >> 6, lane = tid & 63;
  const int m = lane & 15, quad = lane >> 4;

  __shared__ unsigned short B_lds[12288];     // 24576 B
  __shared__ unsigned short A2[64][72];       // 9216 B
  __shared__ float bb2_s[64];
  __shared__ float pb2_s[64];

  // ---- q fragment rows straight to registers (issued first: 8x dwordx4) ----
  // lane (m, quad) owns row wv*16+m, cols quad*8 + qq*32 + [0,8), qq=0..3.
  // Per wave-instruction: 16 rows x one full 128B line each (dense).
  const float* qrow = a.q + ((size_t)i * NN + jbase + wv * 16 + m) * CIN + quad * 8;
  float4 qv[8];
#pragma unroll
  for (int qq = 0; qq < 4; ++qq) {
    qv[2 * qq]     = *(const float4*)(qrow + qq * 32);
    qv[2 * qq + 1] = *(const float4*)(qrow + qq * 32 + 4);
  }

  // ---- pair masks ----
  if (tid < 64) {
    int j = jbase + tid;
    float mc  = a.mc[(size_t)i * NN + j];
    bb2_s[tid] = a.bbm[i] * a.bbm[j] * mc;
    pb2_s[tid] = a.pbm[i] * a.pbm[j] * mc;
  }

  // ---- stage B_pack (ws -> LDS), 1536 int4 ----
  {
    const int4* src = (const int4*)a.b_pack;
    int4* dst = (int4*)B_lds;
#pragma unroll
    for (int r = 0; r < 6; ++r) dst[tid + 256 * r] = src[tid + 256 * r];
  }

  // ---- LayerNorm reduce across the 4 lanes sharing a row ----
  float sum = 0.f, sq = 0.f;
#pragma unroll
  for (int v = 0; v < 8; ++v) {
    float4 t4 = qv[v];
    sum += t4.x + t4.y + t4.z + t4.w;
    sq  += t4.x * t4.x + t4.y * t4.y + t4.z * t4.z + t4.w * t4.w;
  }
  sum += __shfl_xor(sum, 16); sum += __shfl_xor(sum, 32);
  sq  += __shfl_xor(sq, 16);  sq  += __shfl_xor(sq, 32);
  const float mu  = sum * (1.f / 128.f);
  const float var = sq * (1.f / 128.f) - mu * mu;
  const float rs  = rsqrtf(var + 1e-5f);

  // in-register bf16 A-fragments for K-steps 0..3 (gain/shift folded into B)
  short8 af[4];
#pragma unroll
  for (int qq = 0; qq < 4; ++qq) {
    union { short8 s; unsigned int w[4]; } u;
    float4 lo = qv[2 * qq], hi = qv[2 * qq + 1];
    u.w[0] = pk((lo.x - mu) * rs, (lo.y - mu) * rs);
    u.w[1] = pk((lo.z - mu) * rs, (lo.w - mu) * rs);
    u.w[2] = pk((hi.x - mu) * rs, (hi.y - mu) * rs);
    u.w[3] = pk((hi.z - mu) * rs, (hi.w - mu) * rs);
    af[qq] = u.s;
  }

  __syncthreads();   // bb2_s/pb2_s ready

  // ---- dgram tile: contiguous 64*39 f32 span, flat-copied as float2 ----
  {
    const float* base = a.td + ((size_t)i * NN + jbase) * CDG;
    const float2* src = (const float2*)base;   // 1248 float2
    for (int w = tid; w < (64 * CDG) / 2; w += 256) {
      float2 d2 = src[w];
      int f0 = w * 2;
      int p0 = (f0 * 26887) >> 20; int d0 = f0 - p0 * CDG;
      int f1 = f0 + 1;
      int p1 = (f1 * 26887) >> 20; int d1 = f1 - p1 * CDG;
      A2[p0][d0] = f2bf(d2.x * bb2_s[p0]);
      A2[p1][d1] = f2bf(d2.y * bb2_s[p1]);
    }
  }
  // ---- rank-1 columns + zero pad ----
  if (tid < 64) {
    int p = tid;
    size_t gij = (size_t)i * NN + jbase + p;
    float bb = bb2_s[p];
    A2[p][39] = f2bf(pb2_s[p]);
    A2[p][40] = f2bf(a.ux[gij] * bb);
    A2[p][41] = f2bf(a.uy[gij] * bb);
    A2[p][42] = f2bf(a.uz[gij] * bb);
    A2[p][43] = f2bf(bb);
    unsigned int* zp = (unsigned int*)&A2[p][44];   // byte 88, 4-aligned
#pragma unroll
    for (int z = 0; z < 10; ++z) zp[z] = 0;         // cols 44..63
  }
  __syncthreads();

  // ---- MFMA: wave wv -> pairs [wv*16, wv*16+16), 64 channels (4 N-tiles) ----
  f32x4 acc[4];
#pragma unroll
  for (int t = 0; t < 4; ++t) { f32x4 z = {0.f, 0.f, 0.f, 0.f}; acc[t] = z; }
  const unsigned short* Bb = &B_lds[lane * 8];
#pragma unroll
  for (int qq = 0; qq < 4; ++qq) {
#pragma unroll
    for (int t = 0; t < 4; ++t) {
      short8 bfr = *(const short8*)(Bb + (qq * 4 + t) * 512);
      acc[t] = __builtin_amdgcn_mfma_f32_16x16x32_bf16(af[qq], bfr, acc[t], 0, 0, 0);
    }
  }
  const unsigned short* Ab2 = &A2[wv * 16 + m][quad * 8];
#pragma unroll
  for (int q = 4; q < 6; ++q) {
    short8 a8 = *(const short8*)(Ab2 + (q - 4) * 32);
#pragma unroll
    for (int t = 0; t < 4; ++t) {
      short8 bfr = *(const short8*)(Bb + (q * 4 + t) * 512);
      acc[t] = __builtin_amdgcn_mfma_f32_16x16x32_bf16(a8, bfr, acc[t], 0, 0, 0);
    }
  }

  // ---- epilogue: + row_vec[j] + col_vec[i], store float32 ----
  const float* cvp = a.col_vec + (size_t)i * COUT;
#pragma unroll
  for (int t = 0; t < 4; ++t) {
    int n = t * 16 + m;
    float cv = cvp[n];
#pragma unroll
    for (int r = 0; r < 4; ++r) {
      int p = wv * 16 + quad * 4 + r;
      int j = jbase + p;
      float val = acc[t][r] + a.row_vec[j * COUT + n] + cv;
      a.out[((size_t)i * NN + j) * COUT + n] = val;
    }
  }
}

extern "C" void kernel_launch(void* const* d_in, const int* in_sizes, int n_in,
                              void* d_out, int out_size, void* d_ws, size_t ws_size,
                              hipStream_t stream) {
  Args a;
  a.td     = (const float*)d_in[0];
  a.aa     = (const float*)d_in[1];
  a.q      = (const float*)d_in[2];
  a.pbm    = (const float*)d_in[3];
  a.bbm    = (const float*)d_in[4];
  a.mc     = (const float*)d_in[5];
  a.ux     = (const float*)d_in[6];
  a.uy     = (const float*)d_in[7];
  a.uz     = (const float*)d_in[8];
  a.esm    = (const float*)d_in[9];
  a.w_dgram = (const float*)d_in[10]; a.b_dgram = (const float*)d_in[11];
  a.w_aa1   = (const float*)d_in[12]; a.b_aa1   = (const float*)d_in[13];
  a.w_aa2   = (const float*)d_in[14]; a.b_aa2   = (const float*)d_in[15];
  a.ln_g    = (const float*)d_in[16]; a.ln_b    = (const float*)d_in[17];
  a.w_q     = (const float*)d_in[18]; a.b_q     = (const float*)d_in[19];
  a.w_pbm   = (const float*)d_in[20]; a.b_pbm   = (const float*)d_in[21];
  a.w_x     = (const float*)d_in[22]; a.b_x     = (const float*)d_in[23];
  a.w_y     = (const float*)d_in[24]; a.b_y     = (const float*)d_in[25];
  a.w_z     = (const float*)d_in[26]; a.b_z     = (const float*)d_in[27];
  a.w_bb    = (const float*)d_in[28]; a.b_bb    = (const float*)d_in[29];
  a.w_esm1  = (const float*)d_in[30]; a.b_esm1  = (const float*)d_in[31];
  a.w_esm2  = (const float*)d_in[32]; a.b_esm2  = (const float*)d_in[33];
  a.out = (float*)d_out;
  a.row_vec = (float*)d_ws;                       // 768*64 f32
  a.col_vec = a.row_vec + NN * COUT;              // 768*64 f32
  a.b_pack  = (unsigned short*)(a.col_vec + NN * COUT);  // 12288 bf16

  hipLaunchKernelGGL(k_pre, dim3(NN + 1), dim3(256), 0, stream, a);
  hipLaunchKernelGGL(k_main, dim3(12, NN), dim3(256), 0, stream, a);
}

// Round 3
// 725.751 us; speedup vs baseline: 1.1072x; 1.0258x over previous
//
#include <hip/hip_runtime.h>

#define NN 768
#define CIN 128
#define COUT 64
#define CDG 39
#define CAA 22
#define CESM 1280

typedef __attribute__((ext_vector_type(8))) short short8;
typedef __attribute__((ext_vector_type(4))) float f32x4;

__device__ __forceinline__ unsigned short f2bf(float f) {
  union { float f; unsigned int i; } c; c.f = f;
  unsigned int u = c.i;
  u += 0x7fffu + ((u >> 16) & 1u);
  return (unsigned short)(u >> 16);
}
__device__ __forceinline__ unsigned int pk(float a, float b) {
  return (unsigned int)f2bf(a) | ((unsigned int)f2bf(b) << 16);
}

struct Args {
  const float *td, *aa, *q, *pbm, *bbm, *mc, *ux, *uy, *uz, *esm;
  const float *w_dgram, *b_dgram, *w_aa1, *b_aa1, *w_aa2, *b_aa2;
  const float *ln_g, *ln_b, *w_q, *b_q;
  const float *w_pbm, *b_pbm, *w_x, *b_x, *w_y, *b_y, *w_z, *b_z, *w_bb, *b_bb;
  const float *w_esm1, *b_esm1, *w_esm2, *b_esm2;
  float* out;
  float* row_vec; float* col_vec; unsigned short* b_pack;
};

// ---------------------------------------------------------------------------
// Kernel 1: per-residue row/col vectors (aa + esm projections + all biases)
// and the packed B matrix (192 x 64) bf16 in 16x16x32 MFMA B-fragment order.
// B row k: [0,128)=ln_g*w_q (LN gain folded in), [128,167)=w_dgram,
// 167=w_pbm, 168..170=w_x/y/z, 171=w_bb, [172,192)=zero.
// row_vec bias additionally absorbs ln_b @ w_q (LN shift folded in).
// ---------------------------------------------------------------------------
__global__ __launch_bounds__(256) void k_pre(Args a) {
  const int b = blockIdx.x;
  const int tid = threadIdx.x;
  if (b == NN) {
    // B_pack element e = ((q*4+t)*64 + lane)*8 + j  holds  B[k][n] as bf16
    for (int e = tid; e < 12288; e += 256) {
      int jj = e & 7;
      int lane = (e >> 3) & 63;
      int qt = e >> 9;
      int q = qt >> 2, t = qt & 3;
      int k = q * 32 + ((lane >> 4) << 3) + jj;
      int n = t * 16 + (lane & 15);
      float v = 0.f;
      if (k < CIN) v = a.ln_g[k] * a.w_q[k * COUT + n];
      else if (k < CIN + CDG) v = a.w_dgram[(k - CIN) * COUT + n];
      else if (k == 167) v = a.w_pbm[n];
      else if (k == 168) v = a.w_x[n];
      else if (k == 169) v = a.w_y[n];
      else if (k == 170) v = a.w_z[n];
      else if (k == 171) v = a.w_bb[n];
      a.b_pack[e] = f2bf(v);
    }
    return;
  }
  const int wv = tid >> 6, lane = tid & 63;
  float acc1 = 0.f, acc2 = 0.f;
  const int KT = CAA + CESM;           // 1302
  const int SL = (KT + 3) / 4;         // 326
  int k0 = wv * SL;
  int k1 = k0 + SL; if (k1 > KT) k1 = KT;
  for (int k = k0; k < k1; ++k) {
    float v; const float *w1, *w2;
    if (k < CAA) { v = a.aa[b * CAA + k]; w1 = a.w_aa1 + k * COUT; w2 = a.w_aa2 + k * COUT; }
    else { int e = k - CAA; v = a.esm[b * CESM + e]; w1 = a.w_esm1 + e * COUT; w2 = a.w_esm2 + e * COUT; }
    acc1 += v * w1[lane];
    acc2 += v * w2[lane];
  }
  __shared__ float red1[4][64];
  __shared__ float red2[4][64];
  red1[wv][lane] = acc1; red2[wv][lane] = acc2;
  __syncthreads();
  if (wv == 0) {
    float r1 = red1[0][lane] + red1[1][lane] + red1[2][lane] + red1[3][lane];
    float r2 = red2[0][lane] + red2[1][lane] + red2[2][lane] + red2[3][lane];
    // ln_b @ w_q folded into the row bias (zero for ln_b == 0)
    float bq = 0.f;
    for (int c = 0; c < CIN; ++c) bq += a.ln_b[c] * a.w_q[c * COUT + lane];
    float br = a.b_aa1[lane] + a.b_esm1[lane] + a.b_dgram[lane] +
               a.b_pbm[lane] + a.b_x[lane] + a.b_y[lane] +
               a.b_z[lane] + a.b_bb[lane] + a.b_q[lane] + bq;
    float bc = a.b_aa2[lane] + a.b_esm2[lane];
    a.row_vec[b * COUT + lane] = r1 + br;
    a.col_vec[b * COUT + lane] = r2 + bc;
  }
}

// ---------------------------------------------------------------------------
// Kernel 2: main fused kernel. One block = 64 pairs (fixed i, 64 j) x 64 out.
// ENTIRE A side is register-resident, built straight from global:
//  - q: lane (m,quad) loads row wv*16+m cols quad*8+qq*32, LN via shfl_xor.
//  - dgram: lane loads its own 8 bins (chunk 4); quad 0 also bins 32..38,
//    quad 1 the rank-1 extras. bb2/pb2 recomputed per lane (3 scalar loads).
// LDS = B only (24.6 KB) -> 6 blocks/CU LDS-limit; launch_bounds(256,5)
// caps VGPRs at 102 (hand count ~90). ONE barrier total.
// 4 waves x (16 pairs x 64 channels) via mfma_f32_16x16x32_bf16.
// ---------------------------------------------------------------------------
__global__ __launch_bounds__(256, 5) void k_main(Args a) {
  const int jt = blockIdx.x;           // 0..11
  const int i  = blockIdx.y;           // 0..767
  const int jbase = jt * 64;
  const int tid = threadIdx.x;
  const int wv = tid >> 6, lane = tid & 63;
  const int m = lane & 15, quad = lane >> 4;
  const int arow = wv * 16 + m;        // A-side pair row this lane feeds
  const int aj = jbase + arow;

  __shared__ unsigned short B_lds[12288];     // 24576 B — the only LDS

  // ---- stage B_pack (ws -> LDS), 1536 int4 ----
  {
    const int4* src = (const int4*)a.b_pack;
    int4* dst = (int4*)B_lds;
#pragma unroll
    for (int r = 0; r < 6; ++r) dst[tid + 256 * r] = src[tid + 256 * r];
  }

  // ---- q fragment rows straight to registers (8x dwordx4, dense lines) ----
  const float* qrow = a.q + ((size_t)i * NN + aj) * CIN + quad * 8;
  float4 qv[8];
#pragma unroll
  for (int qq = 0; qq < 4; ++qq) {
    qv[2 * qq]     = *(const float4*)(qrow + qq * 32);
    qv[2 * qq + 1] = *(const float4*)(qrow + qq * 32 + 4);
  }

  // ---- per-lane masks (4x redundant across quads; L1-broadcast) ----
  const float mc  = a.mc[(size_t)i * NN + aj];
  const float bb2 = a.bbm[i] * a.bbm[aj] * mc;
  const float pb2 = a.pbm[i] * a.pbm[aj] * mc;

  // ---- dgram chunk-4 bins: lane's own 8 floats ----
  const float* tdr = a.td + ((size_t)i * NN + aj) * CDG;
  float dg[8];
#pragma unroll
  for (int e = 0; e < 8; ++e) dg[e] = tdr[quad * 8 + e];

  // ---- K-chunk 5 fragment (ext cols 32..63): quad-dependent ----
  short8 a5;
  {
    union { short8 s; unsigned int w[4]; } u;
    u.w[0] = 0u; u.w[1] = 0u; u.w[2] = 0u; u.w[3] = 0u;
    if (quad == 0) {               // dgram bins 32..38 + pb2
      float d0 = tdr[32], d1 = tdr[33], d2 = tdr[34], d3 = tdr[35];
      float d4 = tdr[36], d5 = tdr[37], d6 = tdr[38];
      u.w[0] = pk(d0 * bb2, d1 * bb2);
      u.w[1] = pk(d2 * bb2, d3 * bb2);
      u.w[2] = pk(d4 * bb2, d5 * bb2);
      u.w[3] = pk(d6 * bb2, pb2);
    } else if (quad == 1) {        // ux,uy,uz,bb, 0,0,0,0
      size_t gij = (size_t)i * NN + aj;
      float x = a.ux[gij], y = a.uy[gij], z = a.uz[gij];
      u.w[0] = pk(x * bb2, y * bb2);
      u.w[1] = pk(z * bb2, bb2);
    }
    a5 = u.s;
  }

  // ---- K-chunk 4 fragment ----
  short8 a4;
  {
    union { short8 s; unsigned int w[4]; } u;
    u.w[0] = pk(dg[0] * bb2, dg[1] * bb2);
    u.w[1] = pk(dg[2] * bb2, dg[3] * bb2);
    u.w[2] = pk(dg[4] * bb2, dg[5] * bb2);
    u.w[3] = pk(dg[6] * bb2, dg[7] * bb2);
    a4 = u.s;
  }

  // ---- LayerNorm reduce across the 4 lanes sharing a row ----
  float sum = 0.f, sq = 0.f;
#pragma unroll
  for (int v = 0; v < 8; ++v) {
    float4 t4 = qv[v];
    sum += t4.x + t4.y + t4.z + t4.w;
    sq  += t4.x * t4.x + t4.y * t4.y + t4.z * t4.z + t4.w * t4.w;
  }
  sum += __shfl_xor(sum, 16); sum += __shfl_xor(sum, 32);
  sq  += __shfl_xor(sq, 16);  sq  += __shfl_xor(sq, 32);
  const float mu  = sum * (1.f / 128.f);
  const float var = sq * (1.f / 128.f) - mu * mu;
  const float rs  = rsqrtf(var + 1e-5f);

  // in-register bf16 A-fragments for K-chunks 0..3 (gain/shift folded into B)
  short8 af[4];
#pragma unroll
  for (int qq = 0; qq < 4; ++qq) {
    union { short8 s; unsigned int w[4]; } u;
    float4 lo = qv[2 * qq], hi = qv[2 * qq + 1];
    u.w[0] = pk((lo.x - mu) * rs, (lo.y - mu) * rs);
    u.w[1] = pk((lo.z - mu) * rs, (lo.w - mu) * rs);
    u.w[2] = pk((hi.x - mu) * rs, (hi.y - mu) * rs);
    u.w[3] = pk((hi.z - mu) * rs, (hi.w - mu) * rs);
    af[qq] = u.s;
  }

  __syncthreads();   // B_lds ready (single barrier in the kernel)

  // ---- MFMA: wave wv -> pairs [wv*16, wv*16+16), 64 channels (4 N-tiles) ----
  f32x4 acc[4];
#pragma unroll
  for (int t = 0; t < 4; ++t) { f32x4 z = {0.f, 0.f, 0.f, 0.f}; acc[t] = z; }
  const unsigned short* Bb = &B_lds[lane * 8];
#pragma unroll
  for (int qq = 0; qq < 4; ++qq) {
#pragma unroll
    for (int t = 0; t < 4; ++t) {
      short8 bfr = *(const short8*)(Bb + (qq * 4 + t) * 512);
      acc[t] = __builtin_amdgcn_mfma_f32_16x16x32_bf16(af[qq], bfr, acc[t], 0, 0, 0);
    }
  }
#pragma unroll
  for (int t = 0; t < 4; ++t) {
    short8 bfr = *(const short8*)(Bb + (4 * 4 + t) * 512);
    acc[t] = __builtin_amdgcn_mfma_f32_16x16x32_bf16(a4, bfr, acc[t], 0, 0, 0);
  }
#pragma unroll
  for (int t = 0; t < 4; ++t) {
    short8 bfr = *(const short8*)(Bb + (5 * 4 + t) * 512);
    acc[t] = __builtin_amdgcn_mfma_f32_16x16x32_bf16(a5, bfr, acc[t], 0, 0, 0);
  }

  // ---- epilogue: + row_vec[j] + col_vec[i], store float32 ----
  const float* cvp = a.col_vec + (size_t)i * COUT;
#pragma unroll
  for (int t = 0; t < 4; ++t) {
    int n = t * 16 + m;
    float cv = cvp[n];
#pragma unroll
    for (int r = 0; r < 4; ++r) {
      int p = wv * 16 + quad * 4 + r;
      int j = jbase + p;
      float val = acc[t][r] + a.row_vec[j * COUT + n] + cv;
      a.out[((size_t)i * NN + j) * COUT + n] = val;
    }
  }
}

extern "C" void kernel_launch(void* const* d_in, const int* in_sizes, int n_in,
                              void* d_out, int out_size, void* d_ws, size_t ws_size,
                              hipStream_t stream) {
  Args a;
  a.td     = (const float*)d_in[0];
  a.aa     = (const float*)d_in[1];
  a.q      = (const float*)d_in[2];
  a.pbm    = (const float*)d_in[3];
  a.bbm    = (const float*)d_in[4];
  a.mc     = (const float*)d_in[5];
  a.ux     = (const float*)d_in[6];
  a.uy     = (const float*)d_in[7];
  a.uz     = (const float*)d_in[8];
  a.esm    = (const float*)d_in[9];
  a.w_dgram = (const float*)d_in[10]; a.b_dgram = (const float*)d_in[11];
  a.w_aa1   = (const float*)d_in[12]; a.b_aa1   = (const float*)d_in[13];
  a.w_aa2   = (const float*)d_in[14]; a.b_aa2   = (const float*)d_in[15];
  a.ln_g    = (const float*)d_in[16]; a.ln_b    = (const float*)d_in[17];
  a.w_q     = (const float*)d_in[18]; a.b_q     = (const float*)d_in[19];
  a.w_pbm   = (const float*)d_in[20]; a.b_pbm   = (const float*)d_in[21];
  a.w_x     = (const float*)d_in[22]; a.b_x     = (const float*)d_in[23];
  a.w_y     = (const float*)d_in[24]; a.b_y     = (const float*)d_in[25];
  a.w_z     = (const float*)d_in[26]; a.b_z     = (const float*)d_in[27];
  a.w_bb    = (const float*)d_in[28]; a.b_bb    = (const float*)d_in[29];
  a.w_esm1  = (const float*)d_in[30]; a.b_esm1  = (const float*)d_in[31];
  a.w_esm2  = (const float*)d_in[32]; a.b_esm2  = (const float*)d_in[33];
  a.out = (float*)d_out;
  a.row_vec = (float*)d_ws;                       // 768*64 f32
  a.col_vec = a.row_vec + NN * COUT;              // 768*64 f32
  a.b_pack  = (unsigned short*)(a.col_vec + NN * COUT);  // 12288 bf16

  hipLaunchKernelGGL(k_pre, dim3(NN + 1), dim3(256), 0, stream, a);
  hipLaunchKernelGGL(k_main, dim3(12, NN), dim3(256), 0, stream, a);
}

// Round 4
// 724.196 us; speedup vs baseline: 1.1096x; 1.0021x over previous
//
#include <hip/hip_runtime.h>

#define NN 768
#define CIN 128
#define COUT 64
#define CDG 39
#define CAA 22
#define CESM 1280

typedef __attribute__((ext_vector_type(8))) short short8;
typedef __attribute__((ext_vector_type(4))) float f32x4;

__device__ __forceinline__ unsigned short f2bf(float f) {
  union { float f; unsigned int i; } c; c.f = f;
  unsigned int u = c.i;
  u += 0x7fffu + ((u >> 16) & 1u);
  return (unsigned short)(u >> 16);
}
__device__ __forceinline__ unsigned int pk(float a, float b) {
  return (unsigned int)f2bf(a) | ((unsigned int)f2bf(b) << 16);
}

// async global->LDS, 16B per lane; LDS dest is wave-uniform base + lane*16
__device__ __forceinline__ void gl2lds16(const void* g, void* l) {
  __builtin_amdgcn_global_load_lds(
      (const __attribute__((address_space(1))) unsigned int*)g,
      (__attribute__((address_space(3))) unsigned int*)l,
      16, 0, 0);
}

struct Args {
  const float *td, *aa, *q, *pbm, *bbm, *mc, *ux, *uy, *uz, *esm;
  const float *w_dgram, *b_dgram, *w_aa1, *b_aa1, *w_aa2, *b_aa2;
  const float *ln_g, *ln_b, *w_q, *b_q;
  const float *w_pbm, *b_pbm, *w_x, *b_x, *w_y, *b_y, *w_z, *b_z, *w_bb, *b_bb;
  const float *w_esm1, *b_esm1, *w_esm2, *b_esm2;
  float* out;
  float* row_vec; float* col_vec; unsigned short* b_pack;
};

// ---------------------------------------------------------------------------
// Kernel 1: per-residue row/col vectors (aa + esm projections + all biases)
// and the packed B matrix (192 x 64) bf16 in 16x16x32 MFMA B-fragment order.
// B row k: [0,128)=ln_g*w_q (LN gain folded in), [128,167)=w_dgram,
// 167=w_pbm, 168..170=w_x/y/z, 171=w_bb, [172,192)=zero.
// row_vec bias additionally absorbs ln_b @ w_q (LN shift folded in).
// ---------------------------------------------------------------------------
__global__ __launch_bounds__(256) void k_pre(Args a) {
  const int b = blockIdx.x;
  const int tid = threadIdx.x;
  if (b == NN) {
    // B_pack element e = ((q*4+t)*64 + lane)*8 + j  holds  B[k][n] as bf16
    for (int e = tid; e < 12288; e += 256) {
      int jj = e & 7;
      int lane = (e >> 3) & 63;
      int qt = e >> 9;
      int q = qt >> 2, t = qt & 3;
      int k = q * 32 + ((lane >> 4) << 3) + jj;
      int n = t * 16 + (lane & 15);
      float v = 0.f;
      if (k < CIN) v = a.ln_g[k] * a.w_q[k * COUT + n];
      else if (k < CIN + CDG) v = a.w_dgram[(k - CIN) * COUT + n];
      else if (k == 167) v = a.w_pbm[n];
      else if (k == 168) v = a.w_x[n];
      else if (k == 169) v = a.w_y[n];
      else if (k == 170) v = a.w_z[n];
      else if (k == 171) v = a.w_bb[n];
      a.b_pack[e] = f2bf(v);
    }
    return;
  }
  const int wv = tid >> 6, lane = tid & 63;
  float acc1 = 0.f, acc2 = 0.f;
  const int KT = CAA + CESM;           // 1302
  const int SL = (KT + 3) / 4;         // 326
  int k0 = wv * SL;
  int k1 = k0 + SL; if (k1 > KT) k1 = KT;
  for (int k = k0; k < k1; ++k) {
    float v; const float *w1, *w2;
    if (k < CAA) { v = a.aa[b * CAA + k]; w1 = a.w_aa1 + k * COUT; w2 = a.w_aa2 + k * COUT; }
    else { int e = k - CAA; v = a.esm[b * CESM + e]; w1 = a.w_esm1 + e * COUT; w2 = a.w_esm2 + e * COUT; }
    acc1 += v * w1[lane];
    acc2 += v * w2[lane];
  }
  __shared__ float red1[4][64];
  __shared__ float red2[4][64];
  red1[wv][lane] = acc1; red2[wv][lane] = acc2;
  __syncthreads();
  if (wv == 0) {
    float r1 = red1[0][lane] + red1[1][lane] + red1[2][lane] + red1[3][lane];
    float r2 = red2[0][lane] + red2[1][lane] + red2[2][lane] + red2[3][lane];
    // ln_b @ w_q folded into the row bias (zero for ln_b == 0)
    float bq = 0.f;
    for (int c = 0; c < CIN; ++c) bq += a.ln_b[c] * a.w_q[c * COUT + lane];
    float br = a.b_aa1[lane] + a.b_esm1[lane] + a.b_dgram[lane] +
               a.b_pbm[lane] + a.b_x[lane] + a.b_y[lane] +
               a.b_z[lane] + a.b_bb[lane] + a.b_q[lane] + bq;
    float bc = a.b_aa2[lane] + a.b_esm2[lane];
    a.row_vec[b * COUT + lane] = r1 + br;
    a.col_vec[b * COUT + lane] = r2 + bc;
  }
}

// ---------------------------------------------------------------------------
// Kernel 2: main fused kernel. One block = 64 pairs (fixed i, 64 j) x 64 out.
// ENTIRE A side is register-resident, built straight from global:
//  - q: lane (m,quad) loads row wv*16+m cols quad*8+qq*32, LN via shfl_xor.
//  - dgram: lane loads its own 8 bins (chunk 4); quad 0 also bins 32..38,
//    quad 1 the rank-1 extras. bb2/pb2 recomputed per lane (3 scalar loads).
// B staged via global_load_lds (async, no VGPR round-trip, linear copy).
// LDS = B only (24.6 KB) -> 6 blocks/CU; launch_bounds(256,6) caps VGPR
// at 85 (hand count ~65 peak). ONE barrier total.
// ---------------------------------------------------------------------------
__global__ __launch_bounds__(256, 6) void k_main(Args a) {
  const int jt = blockIdx.x;           // 0..11
  const int i  = blockIdx.y;           // 0..767
  const int jbase = jt * 64;
  const int tid = threadIdx.x;
  const int wv = tid >> 6, lane = tid & 63;
  const int m = lane & 15, quad = lane >> 4;
  const int arow = wv * 16 + m;        // A-side pair row this lane feeds
  const int aj = jbase + arow;

  __shared__ unsigned short B_lds[12288];     // 24576 B — the only LDS

  // ---- stage B_pack -> LDS async: wave wv copies 6 contiguous 1KB chunks ----
  {
    const char* src = (const char*)a.b_pack + (size_t)wv * 6144 + lane * 16;
    char* dst = (char*)B_lds + wv * 6144;
#pragma unroll
    for (int r = 0; r < 6; ++r)
      gl2lds16(src + r * 1024, dst + r * 1024);
  }

  // ---- q fragment rows straight to registers (8x dwordx4, dense lines) ----
  const float* qrow = a.q + ((size_t)i * NN + aj) * CIN + quad * 8;
  float4 qv[8];
#pragma unroll
  for (int qq = 0; qq < 4; ++qq) {
    qv[2 * qq]     = *(const float4*)(qrow + qq * 32);
    qv[2 * qq + 1] = *(const float4*)(qrow + qq * 32 + 4);
  }

  // ---- per-lane masks (4x redundant across quads; L1-broadcast) ----
  const float mc  = a.mc[(size_t)i * NN + aj];
  const float bb2 = a.bbm[i] * a.bbm[aj] * mc;
  const float pb2 = a.pbm[i] * a.pbm[aj] * mc;

  // ---- dgram chunk-4 bins: lane's own 8 floats ----
  const float* tdr = a.td + ((size_t)i * NN + aj) * CDG;
  float dg[8];
#pragma unroll
  for (int e = 0; e < 8; ++e) dg[e] = tdr[quad * 8 + e];

  // ---- K-chunk 5 fragment (ext cols 32..63): quad-dependent ----
  short8 a5;
  {
    union { short8 s; unsigned int w[4]; } u;
    u.w[0] = 0u; u.w[1] = 0u; u.w[2] = 0u; u.w[3] = 0u;
    if (quad == 0) {               // dgram bins 32..38 + pb2
      float d0 = tdr[32], d1 = tdr[33], d2 = tdr[34], d3 = tdr[35];
      float d4 = tdr[36], d5 = tdr[37], d6 = tdr[38];
      u.w[0] = pk(d0 * bb2, d1 * bb2);
      u.w[1] = pk(d2 * bb2, d3 * bb2);
      u.w[2] = pk(d4 * bb2, d5 * bb2);
      u.w[3] = pk(d6 * bb2, pb2);
    } else if (quad == 1) {        // ux,uy,uz,bb, 0,0,0,0
      size_t gij = (size_t)i * NN + aj;
      float x = a.ux[gij], y = a.uy[gij], z = a.uz[gij];
      u.w[0] = pk(x * bb2, y * bb2);
      u.w[1] = pk(z * bb2, bb2);
    }
    a5 = u.s;
  }

  // ---- K-chunk 4 fragment ----
  short8 a4;
  {
    union { short8 s; unsigned int w[4]; } u;
    u.w[0] = pk(dg[0] * bb2, dg[1] * bb2);
    u.w[1] = pk(dg[2] * bb2, dg[3] * bb2);
    u.w[2] = pk(dg[4] * bb2, dg[5] * bb2);
    u.w[3] = pk(dg[6] * bb2, dg[7] * bb2);
    a4 = u.s;
  }

  // ---- LayerNorm reduce across the 4 lanes sharing a row ----
  float sum = 0.f, sq = 0.f;
#pragma unroll
  for (int v = 0; v < 8; ++v) {
    float4 t4 = qv[v];
    sum += t4.x + t4.y + t4.z + t4.w;
    sq  += t4.x * t4.x + t4.y * t4.y + t4.z * t4.z + t4.w * t4.w;
  }
  sum += __shfl_xor(sum, 16); sum += __shfl_xor(sum, 32);
  sq  += __shfl_xor(sq, 16);  sq  += __shfl_xor(sq, 32);
  const float mu  = sum * (1.f / 128.f);
  const float var = sq * (1.f / 128.f) - mu * mu;
  const float rs  = rsqrtf(var + 1e-5f);

  // in-register bf16 A-fragments for K-chunks 0..3 (gain/shift folded into B)
  short8 af[4];
#pragma unroll
  for (int qq = 0; qq < 4; ++qq) {
    union { short8 s; unsigned int w[4]; } u;
    float4 lo = qv[2 * qq], hi = qv[2 * qq + 1];
    u.w[0] = pk((lo.x - mu) * rs, (lo.y - mu) * rs);
    u.w[1] = pk((lo.z - mu) * rs, (lo.w - mu) * rs);
    u.w[2] = pk((hi.x - mu) * rs, (hi.y - mu) * rs);
    u.w[3] = pk((hi.z - mu) * rs, (hi.w - mu) * rs);
    af[qq] = u.s;
  }

  __syncthreads();   // B_lds ready (single barrier; drains vmcnt incl. lds-DMA)

  // ---- MFMA: wave wv -> pairs [wv*16, wv*16+16), 64 channels (4 N-tiles) ----
  f32x4 acc[4];
#pragma unroll
  for (int t = 0; t < 4; ++t) { f32x4 z = {0.f, 0.f, 0.f, 0.f}; acc[t] = z; }
  const unsigned short* Bb = &B_lds[lane * 8];
#pragma unroll
  for (int qq = 0; qq < 4; ++qq) {
#pragma unroll
    for (int t = 0; t < 4; ++t) {
      short8 bfr = *(const short8*)(Bb + (qq * 4 + t) * 512);
      acc[t] = __builtin_amdgcn_mfma_f32_16x16x32_bf16(af[qq], bfr, acc[t], 0, 0, 0);
    }
  }
#pragma unroll
  for (int t = 0; t < 4; ++t) {
    short8 bfr = *(const short8*)(Bb + (4 * 4 + t) * 512);
    acc[t] = __builtin_amdgcn_mfma_f32_16x16x32_bf16(a4, bfr, acc[t], 0, 0, 0);
  }
#pragma unroll
  for (int t = 0; t < 4; ++t) {
    short8 bfr = *(const short8*)(Bb + (5 * 4 + t) * 512);
    acc[t] = __builtin_amdgcn_mfma_f32_16x16x32_bf16(a5, bfr, acc[t], 0, 0, 0);
  }

  // ---- epilogue: + row_vec[j] + col_vec[i], store float32 ----
  const float* cvp = a.col_vec + (size_t)i * COUT;
#pragma unroll
  for (int t = 0; t < 4; ++t) {
    int n = t * 16 + m;
    float cv = cvp[n];
#pragma unroll
    for (int r = 0; r < 4; ++r) {
      int p = wv * 16 + quad * 4 + r;
      int j = jbase + p;
      float val = acc[t][r] + a.row_vec[j * COUT + n] + cv;
      a.out[((size_t)i * NN + j) * COUT + n] = val;
    }
  }
}

extern "C" void kernel_launch(void* const* d_in, const int* in_sizes, int n_in,
                              void* d_out, int out_size, void* d_ws, size_t ws_size,
                              hipStream_t stream) {
  Args a;
  a.td     = (const float*)d_in[0];
  a.aa     = (const float*)d_in[1];
  a.q      = (const float*)d_in[2];
  a.pbm    = (const float*)d_in[3];
  a.bbm    = (const float*)d_in[4];
  a.mc     = (const float*)d_in[5];
  a.ux     = (const float*)d_in[6];
  a.uy     = (const float*)d_in[7];
  a.uz     = (const float*)d_in[8];
  a.esm    = (const float*)d_in[9];
  a.w_dgram = (const float*)d_in[10]; a.b_dgram = (const float*)d_in[11];
  a.w_aa1   = (const float*)d_in[12]; a.b_aa1   = (const float*)d_in[13];
  a.w_aa2   = (const float*)d_in[14]; a.b_aa2   = (const float*)d_in[15];
  a.ln_g    = (const float*)d_in[16]; a.ln_b    = (const float*)d_in[17];
  a.w_q     = (const float*)d_in[18]; a.b_q     = (const float*)d_in[19];
  a.w_pbm   = (const float*)d_in[20]; a.b_pbm   = (const float*)d_in[21];
  a.w_x     = (const float*)d_in[22]; a.b_x     = (const float*)d_in[23];
  a.w_y     = (const float*)d_in[24]; a.b_y     = (const float*)d_in[25];
  a.w_z     = (const float*)d_in[26]; a.b_z     = (const float*)d_in[27];
  a.w_bb    = (const float*)d_in[28]; a.b_bb    = (const float*)d_in[29];
  a.w_esm1  = (const float*)d_in[30]; a.b_esm1  = (const float*)d_in[31];
  a.w_esm2  = (const float*)d_in[32]; a.b_esm2  = (const float*)d_in[33];
  a.out = (float*)d_out;
  a.row_vec = (float*)d_ws;                       // 768*64 f32
  a.col_vec = a.row_vec + NN * COUT;              // 768*64 f32
  a.b_pack  = (unsigned short*)(a.col_vec + NN * COUT);  // 12288 bf16

  hipLaunchKernelGGL(k_pre, dim3(NN + 1), dim3(256), 0, stream, a);
  hipLaunchKernelGGL(k_main, dim3(12, NN), dim3(256), 0, stream, a);
}